// Round 1
// baseline (2697.806 us; speedup 1.0000x reference)
//
#include <hip/hip_runtime.h>
#include <math.h>

// Problem constants (B=1)
#define T_ 2048
#define D_ 1024
#define H_ 16
#define N_ 64
#define F_ 4096

static __device__ __forceinline__ float sigf(float x) { return 1.0f / (1.0f + __expf(-x)); }

// ---------------------------------------------------------------------------
// RMSNorm: one block per token row. out = w * x * rsqrt(mean(x^2)+eps)
// If last != nullptr also write row T-1 there (the xn[:, -1] output).
// ---------------------------------------------------------------------------
__global__ __launch_bounds__(256) void rmsnorm_kernel(const float* __restrict__ x,
                                                      const float* __restrict__ w,
                                                      float* __restrict__ out,
                                                      float* __restrict__ last) {
    const int t = blockIdx.x;
    const int tid = threadIdx.x;
    const float4* xr = (const float4*)(x + (size_t)t * D_);
    float4 v = xr[tid];
    float ss = v.x * v.x + v.y * v.y + v.z * v.z + v.w * v.w;
    ss += __shfl_xor(ss, 1);
    ss += __shfl_xor(ss, 2);
    ss += __shfl_xor(ss, 4);
    ss += __shfl_xor(ss, 8);
    ss += __shfl_xor(ss, 16);
    ss += __shfl_xor(ss, 32);
    __shared__ float red[4];
    if ((tid & 63) == 0) red[tid >> 6] = ss;
    __syncthreads();
    float tot = red[0] + red[1] + red[2] + red[3];
    float scale = rsqrtf(tot * (1.0f / (float)D_) + 1e-6f);
    float4 wv = ((const float4*)w)[tid];
    float4 o;
    o.x = wv.x * v.x * scale;
    o.y = wv.y * v.y * scale;
    o.z = wv.z * v.z * scale;
    o.w = wv.w * v.w * scale;
    ((float4*)(out + (size_t)t * D_))[tid] = o;
    if (last != nullptr && t == T_ - 1) ((float4*)last)[tid] = o;
}

// ---------------------------------------------------------------------------
// Token shift: xx = (t==0 ? x_prev : xn[t-1]) - xn[t]; x? = xn + xx*coef?
// One thread per float4; i = t*256 + j.
// ---------------------------------------------------------------------------
__global__ __launch_bounds__(256) void shift_kernel(
    const float* __restrict__ xn, const float* __restrict__ x_prev,
    const float* __restrict__ cr, const float* __restrict__ cw, const float* __restrict__ ck,
    const float* __restrict__ cv, const float* __restrict__ ca, const float* __restrict__ cg,
    float* __restrict__ xr, float* __restrict__ xw, float* __restrict__ xk,
    float* __restrict__ xv, float* __restrict__ xa, float* __restrict__ xg) {
    const int i = blockIdx.x * 256 + threadIdx.x;  // float4 index over T*256
    const int t = i >> 8, j = i & 255;
    const float4* xn4 = (const float4*)xn;
    float4 cur = xn4[i];
    float4 prev = (t == 0) ? ((const float4*)x_prev)[j] : xn4[i - 256];
    float4 xx;
    xx.x = prev.x - cur.x;
    xx.y = prev.y - cur.y;
    xx.z = prev.z - cur.z;
    xx.w = prev.w - cur.w;
#define APPLY(dst, c)                                   \
    {                                                   \
        float4 cc = ((const float4*)c)[j];              \
        float4 o;                                       \
        o.x = cur.x + xx.x * cc.x;                      \
        o.y = cur.y + xx.y * cc.y;                      \
        o.z = cur.z + xx.z * cc.z;                      \
        o.w = cur.w + xx.w * cc.w;                      \
        ((float4*)dst)[i] = o;                          \
    }
    APPLY(xr, cr)
    APPLY(xw, cw)
    APPLY(xk, ck)
    APPLY(xv, cv)
    APPLY(xa, ca)
    APPLY(xg, cg)
#undef APPLY
}

// ---------------------------------------------------------------------------
// Tiled fp32 GEMM: C[M,Nc] = epi(A[M,K] @ B[K,Nc]).
// 64x64 tile / block(256), 4x4 micro-tile, K-tile 16. M must be multiple of 64,
// K multiple of 16, Nc multiple of 4 (column-guarded).
// epi: 0 none, 1 tanh, 2 sig(bias+v), 3 -e^-0.5*sig(bias+v) [w_log],
//      4 vlerp: res + (res2-res)*sig(bias+v), 5 res+v, 6 sig(v), 7 silu(v)
// ---------------------------------------------------------------------------
__global__ __launch_bounds__(256) void gemm_k(
    const float* __restrict__ A, const float* __restrict__ Bm, float* __restrict__ C,
    int M, int K, int Nc, int epi,
    const float* __restrict__ bias, const float* __restrict__ res, const float* __restrict__ res2) {
    __shared__ float As[16][68];  // As[kk][m], +4 pad keeps float4 alignment
    __shared__ float Bs[16][68];  // Bs[kk][n]
    const int t = threadIdx.x;
    const int tx = t & 15, ty = t >> 4;
    const int row0 = blockIdx.y * 64, col0 = blockIdx.x * 64;
    const int a_row = t >> 2, a_k4 = (t & 3) << 2;
    const int b_kk = t >> 4, b_c4 = (t & 15) << 2;

    float acc[4][4];
#pragma unroll
    for (int i = 0; i < 4; i++)
#pragma unroll
        for (int j = 0; j < 4; j++) acc[i][j] = 0.0f;

    for (int k0 = 0; k0 < K; k0 += 16) {
        float4 av = *(const float4*)(A + (size_t)(row0 + a_row) * K + (k0 + a_k4));
        As[a_k4 + 0][a_row] = av.x;
        As[a_k4 + 1][a_row] = av.y;
        As[a_k4 + 2][a_row] = av.z;
        As[a_k4 + 3][a_row] = av.w;
        float4 bv = make_float4(0.f, 0.f, 0.f, 0.f);
        const int bc = col0 + b_c4;
        if (bc + 3 < Nc) bv = *(const float4*)(Bm + (size_t)(k0 + b_kk) * Nc + bc);
        *(float4*)&Bs[b_kk][b_c4] = bv;
        __syncthreads();
#pragma unroll
        for (int kk = 0; kk < 16; kk++) {
            float4 a4 = *(const float4*)&As[kk][ty << 2];
            float4 b4 = *(const float4*)&Bs[kk][tx << 2];
            float ar[4] = {a4.x, a4.y, a4.z, a4.w};
            float br[4] = {b4.x, b4.y, b4.z, b4.w};
#pragma unroll
            for (int i = 0; i < 4; i++)
#pragma unroll
                for (int j = 0; j < 4; j++) acc[i][j] = fmaf(ar[i], br[j], acc[i][j]);
        }
        __syncthreads();
    }

#pragma unroll
    for (int i = 0; i < 4; i++) {
        const int rr = row0 + (ty << 2) + i;
#pragma unroll
        for (int j = 0; j < 4; j++) {
            const int cc = col0 + (tx << 2) + j;
            if (cc < Nc) {
                const size_t idx = (size_t)rr * Nc + cc;
                float val = acc[i][j];
                switch (epi) {
                    case 1: val = tanhf(val); break;
                    case 2: val = sigf(bias[cc] + val); break;
                    case 3: val = -0.60653065971263342f * sigf(bias[cc] + val); break;
                    case 4: {
                        float vr = res[idx];
                        val = vr + (res2[idx] - vr) * sigf(bias[cc] + val);
                    } break;
                    case 5: val = res[idx] + val; break;
                    case 6: val = sigf(val); break;
                    case 7: val = val * sigf(val); break;
                    default: break;
                }
                C[idx] = val;
            }
        }
    }
}

// ---------------------------------------------------------------------------
// kk = normalize_per_head(k * k_k); k *= (1 + (a-1)*k_a). One wave per (t,h).
// Uses RAW k (pre-modification) for kk, as in the reference.
// ---------------------------------------------------------------------------
__global__ __launch_bounds__(64) void kk_kernel(float* __restrict__ k,
                                                const float* __restrict__ a_sig,
                                                const float* __restrict__ k_k,
                                                const float* __restrict__ k_a,
                                                float* __restrict__ kk) {
    const int b = blockIdx.x;
    const int t = b >> 4, h = b & 15;
    const int lane = threadIdx.x;
    const size_t idx = (size_t)t * D_ + h * N_ + lane;
    const int wi = h * N_ + lane;
    const float kraw = k[idx];
    const float kv = kraw * k_k[wi];
    float ss = kv * kv;
    ss += __shfl_xor(ss, 1);
    ss += __shfl_xor(ss, 2);
    ss += __shfl_xor(ss, 4);
    ss += __shfl_xor(ss, 8);
    ss += __shfl_xor(ss, 16);
    ss += __shfl_xor(ss, 32);
    const float nrm = fmaxf(sqrtf(ss), 1e-12f);
    kk[idx] = kv / nrm;
    k[idx] = kraw * (1.0f + (a_sig[idx] - 1.0f) * k_a[wi]);
}

// ---------------------------------------------------------------------------
// RWKV7 sequential scan. Rows of S are independent; lane owns (row, 4 cols).
// Block 256 = 16 rows; 4 blocks per head. sa/o reduced over 16-lane groups.
// Vectors for step t+1 are prefetched during compute of step t.
// ---------------------------------------------------------------------------
__global__ __launch_bounds__(256) void scan_kernel(
    const float* __restrict__ rK, const float* __restrict__ wlog, const float* __restrict__ kv,
    const float* __restrict__ vv, const float* __restrict__ asig, const float* __restrict__ kkn,
    const float* __restrict__ state_in, float* __restrict__ o, float* __restrict__ state_out) {
    const int h = blockIdx.x >> 2, wgp = blockIdx.x & 3;
    const int lane = threadIdx.x & 63, wave = threadIdx.x >> 6;
    const int cg = lane & 15, lrow = lane >> 4;
    const int row = wgp * 16 + wave * 4 + lrow;
    const int col = cg << 2;
    const int hb = h * N_;

    float4 s = *(const float4*)(state_in + h * N_ * N_ + row * N_ + col);

    size_t off = (size_t)hb + col;
    float4 c_r = *(const float4*)(rK + off);
    float4 c_w = *(const float4*)(wlog + off);
    float4 c_k = *(const float4*)(kv + off);
    float4 c_kk = *(const float4*)(kkn + off);
    float4 c_a = *(const float4*)(asig + off);
    float c_v = vv[hb + row];

    for (int t = 0; t < T_; t++) {
        const int tn = (t + 1 < T_) ? t + 1 : t;
        const size_t offn = (size_t)tn * D_ + hb + col;
        float4 n_r = *(const float4*)(rK + offn);
        float4 n_w = *(const float4*)(wlog + offn);
        float4 n_k = *(const float4*)(kv + offn);
        float4 n_kk = *(const float4*)(kkn + offn);
        float4 n_a = *(const float4*)(asig + offn);
        float n_v = vv[(size_t)tn * D_ + hb + row];

        // sa[row] = sum_j S[row][j] * (-kk[j])
        float sap = -(s.x * c_kk.x + s.y * c_kk.y + s.z * c_kk.z + s.w * c_kk.w);
        sap += __shfl_xor(sap, 1);
        sap += __shfl_xor(sap, 2);
        sap += __shfl_xor(sap, 4);
        sap += __shfl_xor(sap, 8);

        float4 d4;
        d4.x = __expf(c_w.x);
        d4.y = __expf(c_w.y);
        d4.z = __expf(c_w.z);
        d4.w = __expf(c_w.w);
        // S = S*decay + sa*bb + v*k   (bb = kk * a_sig)
        s.x = s.x * d4.x + sap * (c_kk.x * c_a.x) + c_v * c_k.x;
        s.y = s.y * d4.y + sap * (c_kk.y * c_a.y) + c_v * c_k.y;
        s.z = s.z * d4.z + sap * (c_kk.z * c_a.z) + c_v * c_k.z;
        s.w = s.w * d4.w + sap * (c_kk.w * c_a.w) + c_v * c_k.w;

        float op = s.x * c_r.x + s.y * c_r.y + s.z * c_r.z + s.w * c_r.w;
        op += __shfl_xor(op, 1);
        op += __shfl_xor(op, 2);
        op += __shfl_xor(op, 4);
        op += __shfl_xor(op, 8);
        if (cg == 0) o[(size_t)t * D_ + hb + row] = op;

        c_r = n_r; c_w = n_w; c_k = n_k; c_kk = n_kk; c_a = n_a; c_v = n_v;
    }
    *(float4*)(state_out + h * N_ * N_ + row * N_ + col) = s;
}

// ---------------------------------------------------------------------------
// bonus + gate: og = (o + (sum_j r*k*r_k) * v) * g. One wave per (t,h).
// ---------------------------------------------------------------------------
__global__ __launch_bounds__(64) void bonus_kernel(const float* __restrict__ o,
                                                   const float* __restrict__ r,
                                                   const float* __restrict__ k,
                                                   const float* __restrict__ v,
                                                   const float* __restrict__ g,
                                                   const float* __restrict__ r_k,
                                                   float* __restrict__ og) {
    const int b = blockIdx.x;
    const int t = b >> 4, h = b & 15;
    const int lane = threadIdx.x;
    const size_t idx = (size_t)t * D_ + h * N_ + lane;
    float c = r[idx] * k[idx] * r_k[h * N_ + lane];
    c += __shfl_xor(c, 1);
    c += __shfl_xor(c, 2);
    c += __shfl_xor(c, 4);
    c += __shfl_xor(c, 8);
    c += __shfl_xor(c, 16);
    c += __shfl_xor(c, 32);
    const float on = o[idx] + c * v[idx];
    og[idx] = on * g[idx];
}

// h = silu_gate * up, in place into a (float4 per thread)
__global__ __launch_bounds__(256) void mul_kernel(float* __restrict__ a, const float* __restrict__ b) {
    const int i = blockIdx.x * 256 + threadIdx.x;
    float4 av = ((float4*)a)[i];
    float4 bv = ((const float4*)b)[i];
    av.x *= bv.x;
    av.y *= bv.y;
    av.z *= bv.z;
    av.w *= bv.w;
    ((float4*)a)[i] = av;
}

// ---------------------------------------------------------------------------
static inline void launch_gemm(const float* A, const float* B, float* C, int M, int K, int Nc,
                               int epi, const float* bias, const float* res, const float* res2,
                               hipStream_t s) {
    dim3 g((Nc + 63) / 64, (M + 63) / 64);
    gemm_k<<<g, 256, 0, s>>>(A, B, C, M, K, Nc, epi, bias, res, res2);
}

extern "C" void kernel_launch(void* const* d_in, const int* in_sizes, int n_in,
                              void* d_out, int out_size, void* d_ws, size_t ws_size,
                              hipStream_t stream) {
    const float* x      = (const float*)d_in[0];
    const float* x_prev = (const float*)d_in[1];
    const float* v_first= (const float*)d_in[2];
    const float* state  = (const float*)d_in[3];
    const float* ln1_w  = (const float*)d_in[4];
    const float* ln2_w  = (const float*)d_in[5];
    const float* x_r    = (const float*)d_in[6];
    const float* x_w    = (const float*)d_in[7];
    const float* x_k    = (const float*)d_in[8];
    const float* x_v    = (const float*)d_in[9];
    const float* x_a    = (const float*)d_in[10];
    const float* x_g    = (const float*)d_in[11];
    const float* w0     = (const float*)d_in[12];
    const float* w1     = (const float*)d_in[13];
    const float* w2     = (const float*)d_in[14];
    const float* a0     = (const float*)d_in[15];
    const float* a1     = (const float*)d_in[16];
    const float* a2     = (const float*)d_in[17];
    const float* v0     = (const float*)d_in[18];
    const float* v1     = (const float*)d_in[19];
    const float* v2     = (const float*)d_in[20];
    const float* g1     = (const float*)d_in[21];
    const float* g2     = (const float*)d_in[22];
    const float* k_k    = (const float*)d_in[23];
    const float* k_a    = (const float*)d_in[24];
    const float* r_k    = (const float*)d_in[25];
    const float* R_     = (const float*)d_in[26];
    const float* K_     = (const float*)d_in[27];
    const float* V_     = (const float*)d_in[28];
    const float* O_     = (const float*)d_in[29];
    const float* gate_w = (const float*)d_in[30];
    const float* up_w   = (const float*)d_in[31];
    const float* down_w = (const float*)d_in[32];

    // workspace layout: 14 units of T*D floats (8MB), then small LoRA buffers.
    // Total ~115 MB.
    float* ws = (float*)d_ws;
    const size_t U = (size_t)T_ * D_;
    float* u0 = ws + 0 * U;   // xn
    float* u1 = ws + 1 * U;   // xr -> o
    float* u2 = ws + 2 * U;   // xw -> og
    float* u3 = ws + 3 * U;   // xk -> x1 (post-attn residual)
    float* u4 = ws + 4 * U;   // xv -> xm
    float* u5 = ws + 5 * U;   // xa ; units 5-8 -> silu(gate) [T,F]
    float* u6 = ws + 6 * U;   // xg
    float* u7 = ws + 7 * U;   // r
    float* u8 = ws + 8 * U;   // k
    float* u9 = ws + 9 * U;   // v ; units 9-12 -> up [T,F]
    float* u10 = ws + 10 * U; // w_log
    float* u11 = ws + 11 * U; // a_sig
    float* u12 = ws + 12 * U; // g
    float* u13 = ws + 13 * U; // kk
    float* lw1 = ws + 14 * U;           // [T,64]
    float* la1 = lw1 + (size_t)T_ * 64; // [T,64]
    float* lv1 = la1 + (size_t)T_ * 64; // [T,32]
    float* lg1 = lv1 + (size_t)T_ * 32; // [T,128]

    float* out_x = (float*)d_out;                       // [T,D]
    float* out_xn_last = out_x + (size_t)T_ * D_;       // [D]
    float* out_state = out_xn_last + D_;                // [H,N,N]

    // 1. ln1 + xn_last output
    rmsnorm_kernel<<<T_, 256, 0, stream>>>(x, ln1_w, u0, out_xn_last);
    // 2. token shift -> xr..xg
    shift_kernel<<<T_, 256, 0, stream>>>(u0, x_prev, x_r, x_w, x_k, x_v, x_a, x_g,
                                         u1, u2, u3, u4, u5, u6);
    // 3-5. r, k, v_raw projections
    launch_gemm(u1, R_, u7, T_, D_, D_, 0, nullptr, nullptr, nullptr, stream);
    launch_gemm(u3, K_, u8, T_, D_, D_, 0, nullptr, nullptr, nullptr, stream);
    launch_gemm(u4, V_, u9, T_, D_, D_, 0, nullptr, nullptr, nullptr, stream);
    // 6-7. w LoRA: lw1 = tanh(xw@w1); w_log = -e^-0.5 * sig(w0 + lw1@w2)
    launch_gemm(u2, w1, lw1, T_, D_, 64, 1, nullptr, nullptr, nullptr, stream);
    launch_gemm(lw1, w2, u10, T_, 64, D_, 3, w0, nullptr, nullptr, stream);
    // 8-9. a LoRA: a_sig = sig(a0 + (xa@a1)@a2)
    launch_gemm(u5, a1, la1, T_, D_, 64, 0, nullptr, nullptr, nullptr, stream);
    launch_gemm(la1, a2, u11, T_, 64, D_, 2, a0, nullptr, nullptr, stream);
    // 10-11. v LoRA + lerp: v = v_raw + (v_first - v_raw)*sig(v0 + (xv@v1)@v2)
    launch_gemm(u4, v1, lv1, T_, D_, 32, 0, nullptr, nullptr, nullptr, stream);
    launch_gemm(lv1, v2, u9, T_, 32, D_, 4, v0, u9, v_first, stream);
    // 12-13. g = sig(xg@g1)@g2
    launch_gemm(u6, g1, lg1, T_, D_, 128, 6, nullptr, nullptr, nullptr, stream);
    launch_gemm(lg1, g2, u12, T_, 128, D_, 0, nullptr, nullptr, nullptr, stream);
    // 14. kk normalize + k modification
    kk_kernel<<<T_ * H_, 64, 0, stream>>>(u8, u11, k_k, k_a, u13);
    // 15. recurrent scan (o -> u1, state_f -> out)
    scan_kernel<<<H_ * 4, 256, 0, stream>>>(u7, u10, u8, u9, u11, u13, state, u1, out_state);
    // 16. bonus + gate: og = (o + bonus)*g -> u2
    bonus_kernel<<<T_ * H_, 64, 0, stream>>>(u1, u7, u8, u9, u12, r_k, u2);
    // 17. x1 = x + og@O_ -> u3
    launch_gemm(u2, O_, u3, T_, D_, D_, 5, nullptr, x, nullptr, stream);
    // 18. ln2 -> xm (u4)
    rmsnorm_kernel<<<T_, 256, 0, stream>>>(u3, ln2_w, u4, nullptr);
    // 19-20. gate (silu) and up
    launch_gemm(u4, gate_w, u5, T_, D_, F_, 7, nullptr, nullptr, nullptr, stream);
    launch_gemm(u4, up_w, u9, T_, D_, F_, 0, nullptr, nullptr, nullptr, stream);
    // 21. h = silu(gate) * up (in place into u5)
    mul_kernel<<<(T_ * F_ / 4) / 256, 256, 0, stream>>>(u5, u9);
    // 22. out = x1 + h@down_w
    launch_gemm(u5, down_w, out_x, T_, F_, D_, 5, nullptr, u3, nullptr, stream);
}

// Round 2
// 1646.597 us; speedup vs baseline: 1.6384x; 1.6384x over previous
//
#include <hip/hip_runtime.h>
#include <math.h>

// Problem constants (B=1)
#define T_ 2048
#define D_ 1024
#define H_ 16
#define N_ 64
#define F_ 4096

typedef __attribute__((ext_vector_type(8))) short bf16x8;
typedef __attribute__((ext_vector_type(4))) float f32x4;

static __device__ __forceinline__ float sigf(float x) { return 1.0f / (1.0f + __expf(-x)); }

static __device__ __forceinline__ ushort f2bf(float f) {
    union { float f; unsigned u; } c; c.f = f;
    unsigned r = (c.u + 0x7FFFu + ((c.u >> 16) & 1u)) >> 16;
    return (ushort)r;
}
static __device__ __forceinline__ float bf2f(ushort h) {
    union { unsigned u; float f; } c; c.u = ((unsigned)h) << 16;
    return c.f;
}

static __device__ __forceinline__ void st4(float* p, float4 v) { *(float4*)p = v; }
static __device__ __forceinline__ void st4(ushort* p, float4 v) {
    ushort4 o; o.x = f2bf(v.x); o.y = f2bf(v.y); o.z = f2bf(v.z); o.w = f2bf(v.w);
    *(ushort4*)p = o;
}
static __device__ __forceinline__ void stC(float* p, float v) { *p = v; }
static __device__ __forceinline__ void stC(ushort* p, float v) { *p = f2bf(v); }

// ---------------------------------------------------------------------------
// RMSNorm: one block per token row. out = w * x * rsqrt(mean(x^2)+eps)
// ---------------------------------------------------------------------------
template <typename OutT>
__global__ __launch_bounds__(256) void rmsnorm_kernel(const float* __restrict__ x,
                                                      const float* __restrict__ w,
                                                      OutT* __restrict__ out,
                                                      float* __restrict__ last) {
    const int t = blockIdx.x;
    const int tid = threadIdx.x;
    const float4* xr = (const float4*)(x + (size_t)t * D_);
    float4 v = xr[tid];
    float ss = v.x * v.x + v.y * v.y + v.z * v.z + v.w * v.w;
    ss += __shfl_xor(ss, 1);
    ss += __shfl_xor(ss, 2);
    ss += __shfl_xor(ss, 4);
    ss += __shfl_xor(ss, 8);
    ss += __shfl_xor(ss, 16);
    ss += __shfl_xor(ss, 32);
    __shared__ float red[4];
    if ((tid & 63) == 0) red[tid >> 6] = ss;
    __syncthreads();
    float tot = red[0] + red[1] + red[2] + red[3];
    float scale = rsqrtf(tot * (1.0f / (float)D_) + 1e-6f);
    float4 wv = ((const float4*)w)[tid];
    float4 o;
    o.x = wv.x * v.x * scale;
    o.y = wv.y * v.y * scale;
    o.z = wv.z * v.z * scale;
    o.w = wv.w * v.w * scale;
    st4(out + (size_t)t * D_ + tid * 4, o);
    if (last != nullptr && t == T_ - 1) ((float4*)last)[tid] = o;
}

// ---------------------------------------------------------------------------
// Token shift -> six bf16 activation buffers (GEMM A operands).
// ---------------------------------------------------------------------------
__global__ __launch_bounds__(256) void shift_kernel(
    const float* __restrict__ xn, const float* __restrict__ x_prev,
    const float* __restrict__ cr, const float* __restrict__ cw, const float* __restrict__ ck,
    const float* __restrict__ cv, const float* __restrict__ ca, const float* __restrict__ cg,
    ushort* __restrict__ xr, ushort* __restrict__ xw, ushort* __restrict__ xk,
    ushort* __restrict__ xv, ushort* __restrict__ xa, ushort* __restrict__ xg) {
    const int i = blockIdx.x * 256 + threadIdx.x;  // float4 index over T*256
    const int t = i >> 8, j = i & 255;
    const float4* xn4 = (const float4*)xn;
    float4 cur = xn4[i];
    float4 prev = (t == 0) ? ((const float4*)x_prev)[j] : xn4[i - 256];
    float4 xx;
    xx.x = prev.x - cur.x;
    xx.y = prev.y - cur.y;
    xx.z = prev.z - cur.z;
    xx.w = prev.w - cur.w;
#define APPLY(dst, c)                                   \
    {                                                   \
        float4 cc = ((const float4*)c)[j];              \
        float4 o;                                       \
        o.x = cur.x + xx.x * cc.x;                      \
        o.y = cur.y + xx.y * cc.y;                      \
        o.z = cur.z + xx.z * cc.z;                      \
        o.w = cur.w + xx.w * cc.w;                      \
        st4(dst + (size_t)i * 4, o);                    \
    }
    APPLY(xr, cr)
    APPLY(xw, cw)
    APPLY(xk, ck)
    APPLY(xv, cv)
    APPLY(xa, ca)
    APPLY(xg, cg)
#undef APPLY
}

// ---------------------------------------------------------------------------
// Weight transpose + cast: in [K,N] fp32 -> out [N,K] bf16. 32x32 tiles.
// ---------------------------------------------------------------------------
__global__ __launch_bounds__(256) void transpose_cast(const float* __restrict__ in,
                                                      ushort* __restrict__ out, int K, int N) {
    __shared__ float tile[32][33];
    const int tx = threadIdx.x & 31, ty = threadIdx.x >> 5;  // 32 x 8
    const int n0 = blockIdx.x * 32, k0 = blockIdx.y * 32;
#pragma unroll
    for (int i = 0; i < 4; i++)
        tile[ty + i * 8][tx] = in[(size_t)(k0 + ty + i * 8) * N + n0 + tx];
    __syncthreads();
#pragma unroll
    for (int i = 0; i < 4; i++)
        out[(size_t)(n0 + ty + i * 8) * K + k0 + tx] = f2bf(tile[tx][ty + i * 8]);
}

// ---------------------------------------------------------------------------
// bf16 MFMA GEMM: C[M,Ntot] = epi(A[M,K] @ BT[Ntot,K]^T).
// 128x128 tile, block 256 (4 waves, 2x2), BK=32, mfma_f32_16x16x32_bf16.
// LDS rows padded to 40 shorts (80B) -> 2-way max bank aliasing (free).
// A fragment: lane holds A[m=lane&15][k=(lane>>4)*8+j]; B same with n=lane&15.
// C/D: col=lane&15, row=(lane>>4)*4+reg.
// M multiple of 128, K multiple of 32; Ntot guarded.
// epi: 0 none, 1 +res, 2 silu, 3 tanh, 4 sig(v), 5 sig(bias+v),
//      6 exp(-e^-0.5*sig(bias+v)) [decay], 7 res+(res2-res)*sig(bias+v) [vlerp]
// ---------------------------------------------------------------------------
template <typename OutT>
__global__ __launch_bounds__(256) void mfma_gemm(
    const ushort* __restrict__ A, const ushort* __restrict__ BT, OutT* __restrict__ C,
    const float* __restrict__ res, const float* __restrict__ res2, const float* __restrict__ bias,
    int M, int Ntot, int K, int epi) {
    __shared__ ushort As[128 * 40];
    __shared__ ushort Bs[128 * 40];
    const int tid = threadIdx.x;
    const int wave = tid >> 6, lane = tid & 63;
    const int wr = wave >> 1, wc = wave & 1;
    const int lrow = lane & 15, quad = lane >> 4;
    const int m0 = blockIdx.y * 128, n0 = blockIdx.x * 128;
    const int sr = tid >> 2;           // staging row 0..63 (and +64)
    const int sc = (tid & 3) << 3;     // staging k offset in elements {0,8,16,24}

    f32x4 acc[4][4] = {};

    for (int k0 = 0; k0 < K; k0 += 32) {
        const float4 av0 = *(const float4*)(A + (size_t)(m0 + sr) * K + k0 + sc);
        const float4 av1 = *(const float4*)(A + (size_t)(m0 + sr + 64) * K + k0 + sc);
        float4 bv0 = make_float4(0.f, 0.f, 0.f, 0.f);
        float4 bv1 = make_float4(0.f, 0.f, 0.f, 0.f);
        if (n0 + sr < Ntot) bv0 = *(const float4*)(BT + (size_t)(n0 + sr) * K + k0 + sc);
        if (n0 + sr + 64 < Ntot) bv1 = *(const float4*)(BT + (size_t)(n0 + sr + 64) * K + k0 + sc);
        __syncthreads();  // previous iter's LDS reads done
        *(float4*)&As[sr * 40 + sc] = av0;
        *(float4*)&As[(sr + 64) * 40 + sc] = av1;
        *(float4*)&Bs[sr * 40 + sc] = bv0;
        *(float4*)&Bs[(sr + 64) * 40 + sc] = bv1;
        __syncthreads();
        bf16x8 af[4], bfr[4];
#pragma unroll
        for (int mi = 0; mi < 4; mi++)
            af[mi] = *(const bf16x8*)&As[(wr * 64 + mi * 16 + lrow) * 40 + quad * 8];
#pragma unroll
        for (int ni = 0; ni < 4; ni++)
            bfr[ni] = *(const bf16x8*)&Bs[(wc * 64 + ni * 16 + lrow) * 40 + quad * 8];
#pragma unroll
        for (int mi = 0; mi < 4; mi++)
#pragma unroll
            for (int ni = 0; ni < 4; ni++)
                acc[mi][ni] = __builtin_amdgcn_mfma_f32_16x16x32_bf16(af[mi], bfr[ni], acc[mi][ni], 0, 0, 0);
    }

#pragma unroll
    for (int mi = 0; mi < 4; mi++) {
#pragma unroll
        for (int r = 0; r < 4; r++) {
            const int row = m0 + wr * 64 + mi * 16 + quad * 4 + r;
#pragma unroll
            for (int ni = 0; ni < 4; ni++) {
                const int col = n0 + wc * 64 + ni * 16 + lrow;
                if (col < Ntot) {
                    const size_t idx = (size_t)row * Ntot + col;
                    float val = acc[mi][ni][r];
                    switch (epi) {
                        case 1: val += res[idx]; break;
                        case 2: val = val * sigf(val); break;
                        case 3: val = tanhf(val); break;
                        case 4: val = sigf(val); break;
                        case 5: val = sigf(bias[col] + val); break;
                        case 6: val = __expf(-0.60653065971263342f * sigf(bias[col] + val)); break;
                        case 7: {
                            float vr = res[idx];
                            val = vr + (res2[idx] - vr) * sigf(bias[col] + val);
                        } break;
                        default: break;
                    }
                    stC(&C[idx], val);
                }
            }
        }
    }
}

// ---------------------------------------------------------------------------
// kk = normalize_per_head(k * k_k); mb = -kk*a_sig; k *= (1+(a-1)*k_a).
// One wave per (t,h). Uses RAW k for kk, as in the reference.
// ---------------------------------------------------------------------------
__global__ __launch_bounds__(64) void kk_kernel(float* __restrict__ k,
                                                const float* __restrict__ a_sig,
                                                const float* __restrict__ k_k,
                                                const float* __restrict__ k_a,
                                                float* __restrict__ kk,
                                                float* __restrict__ mb) {
    const int b = blockIdx.x;
    const int t = b >> 4, h = b & 15;
    const int lane = threadIdx.x;
    const size_t idx = (size_t)t * D_ + h * N_ + lane;
    const int wi = h * N_ + lane;
    const float kraw = k[idx];
    const float kv = kraw * k_k[wi];
    float ss = kv * kv;
    ss += __shfl_xor(ss, 1);
    ss += __shfl_xor(ss, 2);
    ss += __shfl_xor(ss, 4);
    ss += __shfl_xor(ss, 8);
    ss += __shfl_xor(ss, 16);
    ss += __shfl_xor(ss, 32);
    const float nrm = fmaxf(sqrtf(ss), 1e-12f);
    const float kkn = kv / nrm;
    kk[idx] = kkn;
    mb[idx] = -kkn * a_sig[idx];
    k[idx] = kraw * (1.0f + (a_sig[idx] - 1.0f) * k_a[wi]);
}

// ---------------------------------------------------------------------------
// RWKV7 sequential scan, LDS-staged in 16-step double-buffered chunks.
// 64 blocks (4 per head), 256 threads; lane owns (row, 4 cols); sa/o reduced
// over 16-lane groups. decay and mb (= -kk*a) precomputed.
// ---------------------------------------------------------------------------
#define CH 16
__global__ __launch_bounds__(256) void scan_kernel(
    const float* __restrict__ gR, const float* __restrict__ gD, const float* __restrict__ gK,
    const float* __restrict__ gV, const float* __restrict__ gKK, const float* __restrict__ gMB,
    const float* __restrict__ state_in, float* __restrict__ o, float* __restrict__ state_out) {
    const int h = blockIdx.x >> 2, wgp = blockIdx.x & 3;
    const int tid = threadIdx.x;
    const int lane = tid & 63, wave = tid >> 6;
    const int cg = lane & 15, lrow = lane >> 4;
    const int rloc = wave * 4 + lrow;  // 0..15
    const int row = wgp * 16 + rloc;
    const int col = cg << 2;
    const int hb = h * N_;

    __shared__ float sR[2][CH][64], sD[2][CH][64], sK[2][CH][64], sKK[2][CH][64], sMB[2][CH][64];
    __shared__ float sV[2][CH][16];

    float4 s = *(const float4*)(state_in + h * N_ * N_ + row * N_ + col);

    const int lst = tid >> 4;         // step this thread stages
    const int lc4 = (tid & 15) << 2;  // col this thread stages
    float4 pre[5];
    float pre_v;

    // issue global loads for chunk starting at t0 into registers
#define ISSUE(t0)                                                              \
    {                                                                          \
        const size_t gbase = (size_t)((t0) + lst) * D_ + hb + lc4;             \
        pre[0] = *(const float4*)(gR + gbase);                                 \
        pre[1] = *(const float4*)(gD + gbase);                                 \
        pre[2] = *(const float4*)(gK + gbase);                                 \
        pre[3] = *(const float4*)(gKK + gbase);                                \
        pre[4] = *(const float4*)(gMB + gbase);                                \
        pre_v = gV[(size_t)((t0) + lst) * D_ + hb + wgp * 16 + (tid & 15)];    \
    }
#define COMMIT(buf)                                                            \
    {                                                                          \
        *(float4*)&sR[buf][lst][lc4] = pre[0];                                 \
        *(float4*)&sD[buf][lst][lc4] = pre[1];                                 \
        *(float4*)&sK[buf][lst][lc4] = pre[2];                                 \
        *(float4*)&sKK[buf][lst][lc4] = pre[3];                                \
        *(float4*)&sMB[buf][lst][lc4] = pre[4];                                \
        sV[buf][lst][tid & 15] = pre_v;                                        \
    }

    ISSUE(0);
    COMMIT(0);
    __syncthreads();
    int p = 0;
    for (int c = 0; c < T_ / CH; c++) {
        if (c + 1 < T_ / CH) ISSUE((c + 1) * CH);
        const int t0 = c * CH;
#pragma unroll 4
        for (int st = 0; st < CH; st++) {
            float4 d4 = *(const float4*)&sD[p][st][col];
            float4 k4 = *(const float4*)&sK[p][st][col];
            float4 kk4 = *(const float4*)&sKK[p][st][col];
            float4 mb4 = *(const float4*)&sMB[p][st][col];
            float4 r4 = *(const float4*)&sR[p][st][col];
            float vv = sV[p][st][rloc];
            // tmp = s*d + v*k (independent of the reduction)
            float4 tmp;
            tmp.x = fmaf(vv, k4.x, s.x * d4.x);
            tmp.y = fmaf(vv, k4.y, s.y * d4.y);
            tmp.z = fmaf(vv, k4.z, s.z * d4.z);
            tmp.w = fmaf(vv, k4.w, s.w * d4.w);
            // sa' = sum_j S[row][j]*kk[j]  (16-lane reduce)
            float sap = s.x * kk4.x + s.y * kk4.y + s.z * kk4.z + s.w * kk4.w;
            sap += __shfl_xor(sap, 1);
            sap += __shfl_xor(sap, 2);
            sap += __shfl_xor(sap, 4);
            sap += __shfl_xor(sap, 8);
            // S = tmp + sa'*mb   (mb = -kk*a)
            s.x = fmaf(sap, mb4.x, tmp.x);
            s.y = fmaf(sap, mb4.y, tmp.y);
            s.z = fmaf(sap, mb4.z, tmp.z);
            s.w = fmaf(sap, mb4.w, tmp.w);
            // o = S . r  (off critical path)
            float op = s.x * r4.x + s.y * r4.y + s.z * r4.z + s.w * r4.w;
            op += __shfl_xor(op, 1);
            op += __shfl_xor(op, 2);
            op += __shfl_xor(op, 4);
            op += __shfl_xor(op, 8);
            if (cg == 0) o[(size_t)(t0 + st) * D_ + hb + row] = op;
        }
        if (c + 1 < T_ / CH) COMMIT(p ^ 1);
        __syncthreads();
        p ^= 1;
    }
    *(float4*)(state_out + h * N_ * N_ + row * N_ + col) = s;
#undef ISSUE
#undef COMMIT
}

// ---------------------------------------------------------------------------
// bonus + gate: og = bf16((o + (sum_j r*k*r_k) * v) * g). One wave per (t,h).
// ---------------------------------------------------------------------------
__global__ __launch_bounds__(64) void bonus_kernel(const float* __restrict__ o,
                                                   const float* __restrict__ r,
                                                   const float* __restrict__ k,
                                                   const float* __restrict__ v,
                                                   const float* __restrict__ g,
                                                   const float* __restrict__ r_k,
                                                   ushort* __restrict__ og) {
    const int b = blockIdx.x;
    const int t = b >> 4, h = b & 15;
    const int lane = threadIdx.x;
    const size_t idx = (size_t)t * D_ + h * N_ + lane;
    float c = r[idx] * k[idx] * r_k[h * N_ + lane];
    c += __shfl_xor(c, 1);
    c += __shfl_xor(c, 2);
    c += __shfl_xor(c, 4);
    c += __shfl_xor(c, 8);
    c += __shfl_xor(c, 16);
    c += __shfl_xor(c, 32);
    const float on = o[idx] + c * v[idx];
    og[idx] = f2bf(on * g[idx]);
}

// h = gate * up (both bf16), in place into gate
__global__ __launch_bounds__(256) void mulb_kernel(ushort* __restrict__ a, const ushort* __restrict__ b) {
    const int i = blockIdx.x * 256 + threadIdx.x;
    ushort4 av = ((ushort4*)a)[i];
    ushort4 bv = ((const ushort4*)b)[i];
    ushort4 o;
    o.x = f2bf(bf2f(av.x) * bf2f(bv.x));
    o.y = f2bf(bf2f(av.y) * bf2f(bv.y));
    o.z = f2bf(bf2f(av.z) * bf2f(bv.z));
    o.w = f2bf(bf2f(av.w) * bf2f(bv.w));
    ((ushort4*)a)[i] = o;
}

// ---------------------------------------------------------------------------
static inline void tc(const float* in, ushort* out, int K, int N, hipStream_t s) {
    dim3 g(N / 32, K / 32);
    transpose_cast<<<g, 256, 0, s>>>(in, out, K, N);
}
template <typename OutT>
static inline void mm(const ushort* A, const ushort* BT, OutT* C, int M, int Ntot, int K, int epi,
                      const float* res, const float* res2, const float* bias, hipStream_t s) {
    dim3 g((Ntot + 127) / 128, M / 128);
    mfma_gemm<OutT><<<g, 256, 0, s>>>(A, BT, C, res, res2, bias, M, Ntot, K, epi);
}

extern "C" void kernel_launch(void* const* d_in, const int* in_sizes, int n_in,
                              void* d_out, int out_size, void* d_ws, size_t ws_size,
                              hipStream_t stream) {
    const float* x      = (const float*)d_in[0];
    const float* x_prev = (const float*)d_in[1];
    const float* v_first= (const float*)d_in[2];
    const float* state  = (const float*)d_in[3];
    const float* ln1_w  = (const float*)d_in[4];
    const float* ln2_w  = (const float*)d_in[5];
    const float* x_r    = (const float*)d_in[6];
    const float* x_w    = (const float*)d_in[7];
    const float* x_k    = (const float*)d_in[8];
    const float* x_v    = (const float*)d_in[9];
    const float* x_a    = (const float*)d_in[10];
    const float* x_g    = (const float*)d_in[11];
    const float* w0     = (const float*)d_in[12];
    const float* w1     = (const float*)d_in[13];
    const float* w2     = (const float*)d_in[14];
    const float* a0     = (const float*)d_in[15];
    const float* a1     = (const float*)d_in[16];
    const float* a2     = (const float*)d_in[17];
    const float* v0     = (const float*)d_in[18];
    const float* v1     = (const float*)d_in[19];
    const float* v2     = (const float*)d_in[20];
    const float* g1     = (const float*)d_in[21];
    const float* g2     = (const float*)d_in[22];
    const float* k_k    = (const float*)d_in[23];
    const float* k_a    = (const float*)d_in[24];
    const float* r_k    = (const float*)d_in[25];
    const float* R_     = (const float*)d_in[26];
    const float* K_     = (const float*)d_in[27];
    const float* V_     = (const float*)d_in[28];
    const float* O_     = (const float*)d_in[29];
    const float* gate_w = (const float*)d_in[30];
    const float* up_w   = (const float*)d_in[31];
    const float* down_w = (const float*)d_in[32];

    float* ws = (float*)d_ws;
    const size_t U = (size_t)T_ * D_;  // 2M floats
    // fp32 scan-side buffers (freed by MLP time)
    float* u_r  = ws;
    float* u_k  = ws + 1 * U;
    float* u_v  = ws + 2 * U;
    float* u_dc = ws + 3 * U;   // decay = exp(w_log)
    float* u_kk = ws + 4 * U;
    float* u_mb = ws + 5 * U;   // -kk*a
    float* u_g  = ws + 6 * U;
    float* u_ao = ws + 7 * U;   // a_sig, later o
    // bf16 activation region: 6 slots of T*D shorts
    ushort* XB = (ushort*)(ws + 8 * U);
    const size_t TD = U;
    ushort* XR = XB + 0 * TD;
    ushort* XW = XB + 1 * TD;
    ushort* XK = XB + 2 * TD;
    ushort* XV = XB + 3 * TD;
    ushort* XA = XB + 4 * TD;
    ushort* XG = XB + 5 * TD;
    ushort* XM   = XB + 0 * TD;  // reuse XR after r-GEMM
    ushort* OG   = XB + 1 * TD;  // reuse XW after w-LoRA1
    ushort* GATE = XB + 2 * TD;  // reuse XK..XG (8M shorts) after their GEMMs
    ushort* UPB  = (ushort*)ws;  // overlay u_r..u_k (8M shorts) after bonus
    // transposed bf16 weights
    ushort* WT = (ushort*)(ws + 11 * U);
    const size_t DD = (size_t)D_ * D_;   // 1048576
    const size_t DF = (size_t)D_ * F_;   // 4194304
    ushort* WTR = WT;
    ushort* WTK = WTR + DD;
    ushort* WTV = WTK + DD;
    ushort* WTO = WTV + DD;
    ushort* WTG = WTO + DD;
    ushort* WTU = WTG + DF;
    ushort* WTD = WTU + DF;
    ushort* WTw1 = WTD + DF;             // [64,1024]
    ushort* WTw2 = WTw1 + 64 * 1024;     // [1024,64]
    ushort* WTa1 = WTw2 + 64 * 1024;
    ushort* WTa2 = WTa1 + 64 * 1024;
    ushort* WTv1 = WTa2 + 64 * 1024;     // [32,1024]
    ushort* WTv2 = WTv1 + 32 * 1024;     // [1024,32]
    ushort* WTg1 = WTv2 + 32 * 1024;     // [128,1024]
    ushort* WTg2 = WTg1 + 128 * 1024;    // [1024,128]
    // bf16 LoRA stage-1 outputs
    ushort* Lw = WTg2 + 128 * 1024;      // [2048,64]
    ushort* La = Lw + (size_t)T_ * 64;
    ushort* Lv = La + (size_t)T_ * 64;   // [2048,32]
    ushort* Lg = Lv + (size_t)T_ * 32;   // [2048,128]

    float* out_x = (float*)d_out;                  // [T,D]; also holds xn then x1
    float* out_xn_last = out_x + (size_t)T_ * D_;  // [D]
    float* out_state = out_xn_last + D_;           // [H,N,N]

    // --- weight transposes (independent) ---
    tc(R_, WTR, D_, D_, stream);
    tc(K_, WTK, D_, D_, stream);
    tc(V_, WTV, D_, D_, stream);
    tc(O_, WTO, D_, D_, stream);
    tc(gate_w, WTG, D_, F_, stream);
    tc(up_w, WTU, D_, F_, stream);
    tc(down_w, WTD, F_, D_, stream);
    tc(w1, WTw1, D_, 64, stream);
    tc(w2, WTw2, 64, D_, stream);
    tc(a1, WTa1, D_, 64, stream);
    tc(a2, WTa2, 64, D_, stream);
    tc(v1, WTv1, D_, 32, stream);
    tc(v2, WTv2, 32, D_, stream);
    tc(g1, WTg1, D_, 128, stream);
    tc(g2, WTg2, 128, D_, stream);

    // 1. ln1 -> xn (in d_out region) + xn_last
    rmsnorm_kernel<float><<<T_, 256, 0, stream>>>(x, ln1_w, out_x, out_xn_last);
    // 2. token shift -> bf16 xr..xg
    shift_kernel<<<T_, 256, 0, stream>>>(out_x, x_prev, x_r, x_w, x_k, x_v, x_a, x_g,
                                         XR, XW, XK, XV, XA, XG);
    // 3-5. r/k/v projections (fp32 out)
    mm<float>(XR, WTR, u_r, T_, D_, D_, 0, nullptr, nullptr, nullptr, stream);
    mm<float>(XK, WTK, u_k, T_, D_, D_, 0, nullptr, nullptr, nullptr, stream);
    mm<float>(XV, WTV, u_v, T_, D_, D_, 0, nullptr, nullptr, nullptr, stream);
    // 6. LoRA stage-1 (bf16 out)
    mm<ushort>(XW, WTw1, Lw, T_, 64, D_, 3, nullptr, nullptr, nullptr, stream);   // tanh
    mm<ushort>(XA, WTa1, La, T_, 64, D_, 0, nullptr, nullptr, nullptr, stream);
    mm<ushort>(XV, WTv1, Lv, T_, 32, D_, 0, nullptr, nullptr, nullptr, stream);
    mm<ushort>(XG, WTg1, Lg, T_, 128, D_, 4, nullptr, nullptr, nullptr, stream);  // sigmoid
    // 7. LoRA stage-2 with fused epilogues
    mm<float>(Lw, WTw2, u_dc, T_, D_, 64, 6, nullptr, nullptr, w0, stream);       // decay
    mm<float>(La, WTa2, u_ao, T_, D_, 64, 5, nullptr, nullptr, a0, stream);       // a_sig
    mm<float>(Lv, WTv2, u_v, T_, D_, 32, 7, u_v, v_first, v0, stream);            // v lerp
    mm<float>(Lg, WTg2, u_g, T_, D_, 128, 0, nullptr, nullptr, nullptr, stream);  // g
    // 8. kk / mb / k-mod
    kk_kernel<<<T_ * H_, 64, 0, stream>>>(u_k, u_ao, k_k, k_a, u_kk, u_mb);
    // 9. recurrent scan: o -> u_ao, state_f -> out
    scan_kernel<<<H_ * 4, 256, 0, stream>>>(u_r, u_dc, u_k, u_v, u_kk, u_mb, state, u_ao, out_state);
    // 10. bonus + gate -> OG bf16
    bonus_kernel<<<T_ * H_, 64, 0, stream>>>(u_ao, u_r, u_k, u_v, u_g, r_k, OG);
    // 11. x1 = x + og@O_ -> d_out (overwrites xn, no longer needed)
    mm<float>(OG, WTO, out_x, T_, D_, D_, 1, x, nullptr, nullptr, stream);
    // 12. ln2 -> xm bf16
    rmsnorm_kernel<ushort><<<T_, 256, 0, stream>>>(out_x, ln2_w, XM, nullptr);
    // 13. MLP
    mm<ushort>(XM, WTG, GATE, T_, F_, D_, 2, nullptr, nullptr, nullptr, stream);  // silu
    mm<ushort>(XM, WTU, UPB, T_, F_, D_, 0, nullptr, nullptr, nullptr, stream);
    mulb_kernel<<<(T_ * F_ / 4) / 256, 256, 0, stream>>>(GATE, UPB);
    // 14. out = x1 + h@down_w  (in-place residual on d_out)
    mm<float>(GATE, WTD, out_x, T_, D_, F_, 1, out_x, nullptr, nullptr, stream);
}

// Round 3
// 1053.409 us; speedup vs baseline: 2.5610x; 1.5631x over previous
//
#include <hip/hip_runtime.h>
#include <math.h>

// Problem constants (B=1)
#define T_ 2048
#define D_ 1024
#define H_ 16
#define N_ 64
#define F_ 4096
#define NCHUNK 32
#define CLEN 64

typedef __attribute__((ext_vector_type(8))) short bf16x8;
typedef __attribute__((ext_vector_type(4))) float f32x4;

static __device__ __forceinline__ float sigf(float x) { return 1.0f / (1.0f + __expf(-x)); }

static __device__ __forceinline__ ushort f2bf(float f) {
    union { float f; unsigned u; } c; c.f = f;
    unsigned r = (c.u + 0x7FFFu + ((c.u >> 16) & 1u)) >> 16;
    return (ushort)r;
}
static __device__ __forceinline__ float bf2f(ushort h) {
    union { unsigned u; float f; } c; c.u = ((unsigned)h) << 16;
    return c.f;
}

static __device__ __forceinline__ void st4(float* p, float4 v) { *(float4*)p = v; }
static __device__ __forceinline__ void st4(ushort* p, float4 v) {
    ushort4 o; o.x = f2bf(v.x); o.y = f2bf(v.y); o.z = f2bf(v.z); o.w = f2bf(v.w);
    *(ushort4*)p = o;
}
static __device__ __forceinline__ void stC(float* p, float v) { *p = v; }
static __device__ __forceinline__ void stC(ushort* p, float v) { *p = f2bf(v); }

// ---------------------------------------------------------------------------
// RMSNorm: one block per token row. out = w * x * rsqrt(mean(x^2)+eps)
// ---------------------------------------------------------------------------
template <typename OutT>
__global__ __launch_bounds__(256) void rmsnorm_kernel(const float* __restrict__ x,
                                                      const float* __restrict__ w,
                                                      OutT* __restrict__ out,
                                                      float* __restrict__ last) {
    const int t = blockIdx.x;
    const int tid = threadIdx.x;
    const float4* xr = (const float4*)(x + (size_t)t * D_);
    float4 v = xr[tid];
    float ss = v.x * v.x + v.y * v.y + v.z * v.z + v.w * v.w;
    ss += __shfl_xor(ss, 1);
    ss += __shfl_xor(ss, 2);
    ss += __shfl_xor(ss, 4);
    ss += __shfl_xor(ss, 8);
    ss += __shfl_xor(ss, 16);
    ss += __shfl_xor(ss, 32);
    __shared__ float red[4];
    if ((tid & 63) == 0) red[tid >> 6] = ss;
    __syncthreads();
    float tot = red[0] + red[1] + red[2] + red[3];
    float scale = rsqrtf(tot * (1.0f / (float)D_) + 1e-6f);
    float4 wv = ((const float4*)w)[tid];
    float4 o;
    o.x = wv.x * v.x * scale;
    o.y = wv.y * v.y * scale;
    o.z = wv.z * v.z * scale;
    o.w = wv.w * v.w * scale;
    st4(out + (size_t)t * D_ + tid * 4, o);
    if (last != nullptr && t == T_ - 1) ((float4*)last)[tid] = o;
}

// ---------------------------------------------------------------------------
// Token shift -> six bf16 activation buffers (GEMM A operands).
// ---------------------------------------------------------------------------
__global__ __launch_bounds__(256) void shift_kernel(
    const float* __restrict__ xn, const float* __restrict__ x_prev,
    const float* __restrict__ cr, const float* __restrict__ cw, const float* __restrict__ ck,
    const float* __restrict__ cv, const float* __restrict__ ca, const float* __restrict__ cg,
    ushort* __restrict__ xr, ushort* __restrict__ xw, ushort* __restrict__ xk,
    ushort* __restrict__ xv, ushort* __restrict__ xa, ushort* __restrict__ xg) {
    const int i = blockIdx.x * 256 + threadIdx.x;  // float4 index over T*256
    const int t = i >> 8, j = i & 255;
    const float4* xn4 = (const float4*)xn;
    float4 cur = xn4[i];
    float4 prev = (t == 0) ? ((const float4*)x_prev)[j] : xn4[i - 256];
    float4 xx;
    xx.x = prev.x - cur.x;
    xx.y = prev.y - cur.y;
    xx.z = prev.z - cur.z;
    xx.w = prev.w - cur.w;
#define APPLY(dst, c)                                   \
    {                                                   \
        float4 cc = ((const float4*)c)[j];              \
        float4 o;                                       \
        o.x = cur.x + xx.x * cc.x;                      \
        o.y = cur.y + xx.y * cc.y;                      \
        o.z = cur.z + xx.z * cc.z;                      \
        o.w = cur.w + xx.w * cc.w;                      \
        st4(dst + (size_t)i * 4, o);                    \
    }
    APPLY(xr, cr)
    APPLY(xw, cw)
    APPLY(xk, ck)
    APPLY(xv, cv)
    APPLY(xa, ca)
    APPLY(xg, cg)
#undef APPLY
}

// ---------------------------------------------------------------------------
// Weight transpose + cast: in [K,N] fp32 -> out [N,K] bf16. 32x32 tiles.
// ---------------------------------------------------------------------------
__global__ __launch_bounds__(256) void transpose_cast(const float* __restrict__ in,
                                                      ushort* __restrict__ out, int K, int N) {
    __shared__ float tile[32][33];
    const int tx = threadIdx.x & 31, ty = threadIdx.x >> 5;  // 32 x 8
    const int n0 = blockIdx.x * 32, k0 = blockIdx.y * 32;
#pragma unroll
    for (int i = 0; i < 4; i++)
        tile[ty + i * 8][tx] = in[(size_t)(k0 + ty + i * 8) * N + n0 + tx];
    __syncthreads();
#pragma unroll
    for (int i = 0; i < 4; i++)
        out[(size_t)(n0 + ty + i * 8) * K + k0 + tx] = f2bf(tile[tx][ty + i * 8]);
}

// ---------------------------------------------------------------------------
// bf16 MFMA GEMM: C[M,Ntot] = epi(A[M,K] @ BT[Ntot,K]^T).
// 128x128 tile, block 256 (4 waves, 2x2), BK=32, mfma_f32_16x16x32_bf16.
// epi: 0 none, 1 +res, 2 silu, 3 tanh, 4 sig(v), 5 sig(bias+v),
//      6 exp(-e^-0.5*sig(bias+v)) [decay], 7 res+(res2-res)*sig(bias+v) [vlerp]
// ---------------------------------------------------------------------------
template <typename OutT>
__global__ __launch_bounds__(256) void mfma_gemm(
    const ushort* __restrict__ A, const ushort* __restrict__ BT, OutT* __restrict__ C,
    const float* __restrict__ res, const float* __restrict__ res2, const float* __restrict__ bias,
    int M, int Ntot, int K, int epi) {
    __shared__ ushort As[128 * 40];
    __shared__ ushort Bs[128 * 40];
    const int tid = threadIdx.x;
    const int wave = tid >> 6, lane = tid & 63;
    const int wr = wave >> 1, wc = wave & 1;
    const int lrow = lane & 15, quad = lane >> 4;
    const int m0 = blockIdx.y * 128, n0 = blockIdx.x * 128;
    const int sr = tid >> 2;           // staging row 0..63 (and +64)
    const int sc = (tid & 3) << 3;     // staging k offset in elements {0,8,16,24}

    f32x4 acc[4][4] = {};

    for (int k0 = 0; k0 < K; k0 += 32) {
        const float4 av0 = *(const float4*)(A + (size_t)(m0 + sr) * K + k0 + sc);
        const float4 av1 = *(const float4*)(A + (size_t)(m0 + sr + 64) * K + k0 + sc);
        float4 bv0 = make_float4(0.f, 0.f, 0.f, 0.f);
        float4 bv1 = make_float4(0.f, 0.f, 0.f, 0.f);
        if (n0 + sr < Ntot) bv0 = *(const float4*)(BT + (size_t)(n0 + sr) * K + k0 + sc);
        if (n0 + sr + 64 < Ntot) bv1 = *(const float4*)(BT + (size_t)(n0 + sr + 64) * K + k0 + sc);
        __syncthreads();  // previous iter's LDS reads done
        *(float4*)&As[sr * 40 + sc] = av0;
        *(float4*)&As[(sr + 64) * 40 + sc] = av1;
        *(float4*)&Bs[sr * 40 + sc] = bv0;
        *(float4*)&Bs[(sr + 64) * 40 + sc] = bv1;
        __syncthreads();
        bf16x8 af[4], bfr[4];
#pragma unroll
        for (int mi = 0; mi < 4; mi++)
            af[mi] = *(const bf16x8*)&As[(wr * 64 + mi * 16 + lrow) * 40 + quad * 8];
#pragma unroll
        for (int ni = 0; ni < 4; ni++)
            bfr[ni] = *(const bf16x8*)&Bs[(wc * 64 + ni * 16 + lrow) * 40 + quad * 8];
#pragma unroll
        for (int mi = 0; mi < 4; mi++)
#pragma unroll
            for (int ni = 0; ni < 4; ni++)
                acc[mi][ni] = __builtin_amdgcn_mfma_f32_16x16x32_bf16(af[mi], bfr[ni], acc[mi][ni], 0, 0, 0);
    }

#pragma unroll
    for (int mi = 0; mi < 4; mi++) {
#pragma unroll
        for (int r = 0; r < 4; r++) {
            const int row = m0 + wr * 64 + mi * 16 + quad * 4 + r;
#pragma unroll
            for (int ni = 0; ni < 4; ni++) {
                const int col = n0 + wc * 64 + ni * 16 + lrow;
                if (col < Ntot) {
                    const size_t idx = (size_t)row * Ntot + col;
                    float val = acc[mi][ni][r];
                    switch (epi) {
                        case 1: val += res[idx]; break;
                        case 2: val = val * sigf(val); break;
                        case 3: val = tanhf(val); break;
                        case 4: val = sigf(val); break;
                        case 5: val = sigf(bias[col] + val); break;
                        case 6: val = __expf(-0.60653065971263342f * sigf(bias[col] + val)); break;
                        case 7: {
                            float vr = res[idx];
                            val = vr + (res2[idx] - vr) * sigf(bias[col] + val);
                        } break;
                        default: break;
                    }
                    stC(&C[idx], val);
                }
            }
        }
    }
}

// ---------------------------------------------------------------------------
// kk = normalize_per_head(k * k_k); mb = -kk*a_sig; k *= (1+(a-1)*k_a).
// ---------------------------------------------------------------------------
__global__ __launch_bounds__(64) void kk_kernel(float* __restrict__ k,
                                                const float* __restrict__ a_sig,
                                                const float* __restrict__ k_k,
                                                const float* __restrict__ k_a,
                                                float* __restrict__ kk,
                                                float* __restrict__ mb) {
    const int b = blockIdx.x;
    const int t = b >> 4, h = b & 15;
    const int lane = threadIdx.x;
    const size_t idx = (size_t)t * D_ + h * N_ + lane;
    const int wi = h * N_ + lane;
    const float kraw = k[idx];
    const float kv = kraw * k_k[wi];
    float ss = kv * kv;
    ss += __shfl_xor(ss, 1);
    ss += __shfl_xor(ss, 2);
    ss += __shfl_xor(ss, 4);
    ss += __shfl_xor(ss, 8);
    ss += __shfl_xor(ss, 16);
    ss += __shfl_xor(ss, 32);
    const float nrm = fmaxf(sqrtf(ss), 1e-12f);
    const float kkn = kv / nrm;
    kk[idx] = kkn;
    mb[idx] = -kkn * a_sig[idx];
    k[idx] = kraw * (1.0f + (a_sig[idx] - 1.0f) * k_a[wi]);
}

// ---------------------------------------------------------------------------
// Chunked scan pass 1. Recurrence per step: S <- S*diag(d) + (S.kk)*mb + v k^T.
// Per (chunk c, head h): evolve P (init I, no vk term) and L (init 0), storing
// per-step dots z_t = P_t r_t (P-blocks) and o_local_t = L_t r_t (L-blocks),
// plus final P_c, L_c. Grid 4096 = 32 chunks x 16 heads x 8 row-blocks
// (rb<4: L rows, rb>=4: P rows; 16 rows/block, 16 lanes/row, 4 cols/lane).
// ---------------------------------------------------------------------------
__global__ __launch_bounds__(256) void scan_pass1(
    const float* __restrict__ gR, const float* __restrict__ gD, const float* __restrict__ gK,
    const float* __restrict__ gV, const float* __restrict__ gKK, const float* __restrict__ gMB,
    float* __restrict__ Pbuf, float* __restrict__ Lbuf,
    float* __restrict__ zbuf, float* __restrict__ olbuf) {
    const int rb = blockIdx.x & 7;
    const int h = (blockIdx.x >> 3) & 15;
    const int c = blockIdx.x >> 7;
    const bool isp = rb >= 4;
    const int wgp = rb & 3;
    const int tid = threadIdx.x;
    const int lane = tid & 63, wave = tid >> 6;
    const int cg = lane & 15, lrow = lane >> 4;
    const int row = wgp * 16 + wave * 4 + lrow;  // 0..63
    const int col = cg << 2;
    const int hb = h * N_;
    const int t0 = c * CLEN;

    float4 s;
    if (isp) {
        s.x = (col + 0 == row) ? 1.0f : 0.0f;
        s.y = (col + 1 == row) ? 1.0f : 0.0f;
        s.z = (col + 2 == row) ? 1.0f : 0.0f;
        s.w = (col + 3 == row) ? 1.0f : 0.0f;
    } else {
        s = make_float4(0.f, 0.f, 0.f, 0.f);
    }
    float* __restrict__ dotOut = isp ? zbuf : olbuf;

    size_t gb = (size_t)t0 * D_ + hb + col;
    float4 c_r = *(const float4*)(gR + gb);
    float4 c_d = *(const float4*)(gD + gb);
    float4 c_k = *(const float4*)(gK + gb);
    float4 c_kk = *(const float4*)(gKK + gb);
    float4 c_mb = *(const float4*)(gMB + gb);
    float c_v = isp ? 0.0f : gV[(size_t)t0 * D_ + hb + row];

    for (int t = t0; t < t0 + CLEN; t++) {
        const int tn = (t + 1 < t0 + CLEN) ? t + 1 : t;
        const size_t gn = (size_t)tn * D_ + hb + col;
        float4 n_r = *(const float4*)(gR + gn);
        float4 n_d = *(const float4*)(gD + gn);
        float4 n_k = *(const float4*)(gK + gn);
        float4 n_kk = *(const float4*)(gKK + gn);
        float4 n_mb = *(const float4*)(gMB + gn);
        float n_v = isp ? 0.0f : gV[(size_t)tn * D_ + hb + row];

        // tmp = s*d + v*k (independent of the reduction)
        float4 tmp;
        tmp.x = fmaf(c_v, c_k.x, s.x * c_d.x);
        tmp.y = fmaf(c_v, c_k.y, s.y * c_d.y);
        tmp.z = fmaf(c_v, c_k.z, s.z * c_d.z);
        tmp.w = fmaf(c_v, c_k.w, s.w * c_d.w);
        // sa' = sum_j S[row][j]*kk[j]  (16-lane reduce)
        float sap = s.x * c_kk.x + s.y * c_kk.y + s.z * c_kk.z + s.w * c_kk.w;
        sap += __shfl_xor(sap, 1);
        sap += __shfl_xor(sap, 2);
        sap += __shfl_xor(sap, 4);
        sap += __shfl_xor(sap, 8);
        // S = tmp + sa'*mb
        s.x = fmaf(sap, c_mb.x, tmp.x);
        s.y = fmaf(sap, c_mb.y, tmp.y);
        s.z = fmaf(sap, c_mb.z, tmp.z);
        s.w = fmaf(sap, c_mb.w, tmp.w);
        // dot with r
        float op = s.x * c_r.x + s.y * c_r.y + s.z * c_r.z + s.w * c_r.w;
        op += __shfl_xor(op, 1);
        op += __shfl_xor(op, 2);
        op += __shfl_xor(op, 4);
        op += __shfl_xor(op, 8);
        if (cg == 0) dotOut[(size_t)t * D_ + hb + row] = op;

        c_r = n_r; c_d = n_d; c_k = n_k; c_kk = n_kk; c_mb = n_mb; c_v = n_v;
    }
    float* __restrict__ sd = isp ? Pbuf : Lbuf;
    *(float4*)(sd + ((size_t)c * 16 + h) * 4096 + row * 64 + col) = s;
}

// ---------------------------------------------------------------------------
// Serial chunk combine: S_{c+1} = S_c @ P_c + L_c, S_0 = state_in.
// Stores S_start (transposed) per chunk for the fix pass; final -> state_out.
// Grid 64 = 16 heads x 4 row-groups of 16 rows.
// ---------------------------------------------------------------------------
__global__ __launch_bounds__(256) void scan_combine(
    const float* __restrict__ state_in, const float* __restrict__ Pbuf,
    const float* __restrict__ Lbuf, float* __restrict__ SstT, float* __restrict__ state_out) {
    const int h = blockIdx.x >> 2, rg = blockIdx.x & 3;
    const int tid = threadIdx.x;
    const int i = tid >> 4, j4 = (tid & 15) << 2;
    const int gi = rg * 16 + i;
    __shared__ float Sl[16][68];
    __shared__ float Pl[64][68];

    float4 sv = *(const float4*)(state_in + (size_t)h * 4096 + gi * 64 + j4);
    *(float4*)&Sl[i][j4] = sv;
    __syncthreads();

    for (int c = 0; c < NCHUNK; c++) {
        const size_t cb = ((size_t)c * 16 + h) * 4096;
        float4 scur = *(const float4*)&Sl[i][j4];
        // store S_start transposed: SstT[j][i] = S[i][j]
        SstT[cb + (size_t)(j4 + 0) * 64 + gi] = scur.x;
        SstT[cb + (size_t)(j4 + 1) * 64 + gi] = scur.y;
        SstT[cb + (size_t)(j4 + 2) * 64 + gi] = scur.z;
        SstT[cb + (size_t)(j4 + 3) * 64 + gi] = scur.w;
        // stage P_c
#pragma unroll
        for (int q = 0; q < 4; q++) {
            const int pr = (tid >> 4) + q * 16;
            *(float4*)&Pl[pr][j4] = *(const float4*)(Pbuf + cb + (size_t)pr * 64 + j4);
        }
        __syncthreads();
        float4 acc = *(const float4*)(Lbuf + cb + (size_t)gi * 64 + j4);
#pragma unroll 8
        for (int m = 0; m < 64; m++) {
            const float smv = Sl[i][m];
            const float4 p4 = *(const float4*)&Pl[m][j4];
            acc.x = fmaf(smv, p4.x, acc.x);
            acc.y = fmaf(smv, p4.y, acc.y);
            acc.z = fmaf(smv, p4.z, acc.z);
            acc.w = fmaf(smv, p4.w, acc.w);
        }
        __syncthreads();
        *(float4*)&Sl[i][j4] = acc;
        __syncthreads();
    }
    *(float4*)(state_out + (size_t)h * 4096 + gi * 64 + j4) = *(const float4*)&Sl[i][j4];
}

// ---------------------------------------------------------------------------
// Fix pass: o[t] = o_local[t] + S_start_c @ z[t] (per head).
// Grid 2048 = 128 token-groups (16 tokens) x 16 heads.
// ---------------------------------------------------------------------------
__global__ __launch_bounds__(256) void scan_fix(
    const float* __restrict__ zbuf, const float* __restrict__ olbuf,
    const float* __restrict__ SstT, float* __restrict__ o) {
    const int tg = blockIdx.x >> 4, h = blockIdx.x & 15;
    const int hb = h * N_;
    const int tid = threadIdx.x;
    const int tok = tid >> 4, i4 = (tid & 15) << 2;
    const int tbase = tg * 16;
    const int c = tbase >> 6;
    __shared__ float zl[16][68];
    __shared__ float Sl[64][68];

    *(float4*)&zl[tok][i4] = *(const float4*)(zbuf + (size_t)(tbase + tok) * D_ + hb + i4);
    const size_t cb = ((size_t)c * 16 + h) * 4096;
#pragma unroll
    for (int q = 0; q < 4; q++) {
        const int jr = (tid >> 4) + q * 16;
        *(float4*)&Sl[jr][i4] = *(const float4*)(SstT + cb + (size_t)jr * 64 + i4);
    }
    __syncthreads();
    float4 acc = *(const float4*)(olbuf + (size_t)(tbase + tok) * D_ + hb + i4);
#pragma unroll 8
    for (int j = 0; j < 64; j++) {
        const float zv = zl[tok][j];
        const float4 p4 = *(const float4*)&Sl[j][i4];
        acc.x = fmaf(zv, p4.x, acc.x);
        acc.y = fmaf(zv, p4.y, acc.y);
        acc.z = fmaf(zv, p4.z, acc.z);
        acc.w = fmaf(zv, p4.w, acc.w);
    }
    *(float4*)(o + (size_t)(tbase + tok) * D_ + hb + i4) = acc;
}

// ---------------------------------------------------------------------------
// bonus + gate: og = bf16((o + (sum_j r*k*r_k) * v) * g). One wave per (t,h).
// ---------------------------------------------------------------------------
__global__ __launch_bounds__(64) void bonus_kernel(const float* __restrict__ o,
                                                   const float* __restrict__ r,
                                                   const float* __restrict__ k,
                                                   const float* __restrict__ v,
                                                   const float* __restrict__ g,
                                                   const float* __restrict__ r_k,
                                                   ushort* __restrict__ og) {
    const int b = blockIdx.x;
    const int t = b >> 4, h = b & 15;
    const int lane = threadIdx.x;
    const size_t idx = (size_t)t * D_ + h * N_ + lane;
    float c = r[idx] * k[idx] * r_k[h * N_ + lane];
    c += __shfl_xor(c, 1);
    c += __shfl_xor(c, 2);
    c += __shfl_xor(c, 4);
    c += __shfl_xor(c, 8);
    c += __shfl_xor(c, 16);
    c += __shfl_xor(c, 32);
    const float on = o[idx] + c * v[idx];
    og[idx] = f2bf(on * g[idx]);
}

// h = gate * up (both bf16), in place into gate
__global__ __launch_bounds__(256) void mulb_kernel(ushort* __restrict__ a, const ushort* __restrict__ b) {
    const int i = blockIdx.x * 256 + threadIdx.x;
    ushort4 av = ((ushort4*)a)[i];
    ushort4 bv = ((const ushort4*)b)[i];
    ushort4 o;
    o.x = f2bf(bf2f(av.x) * bf2f(bv.x));
    o.y = f2bf(bf2f(av.y) * bf2f(bv.y));
    o.z = f2bf(bf2f(av.z) * bf2f(bv.z));
    o.w = f2bf(bf2f(av.w) * bf2f(bv.w));
    ((ushort4*)a)[i] = o;
}

// ---------------------------------------------------------------------------
static inline void tc(const float* in, ushort* out, int K, int N, hipStream_t s) {
    dim3 g(N / 32, K / 32);
    transpose_cast<<<g, 256, 0, s>>>(in, out, K, N);
}
template <typename OutT>
static inline void mm(const ushort* A, const ushort* BT, OutT* C, int M, int Ntot, int K, int epi,
                      const float* res, const float* res2, const float* bias, hipStream_t s) {
    dim3 g((Ntot + 127) / 128, M / 128);
    mfma_gemm<OutT><<<g, 256, 0, s>>>(A, BT, C, res, res2, bias, M, Ntot, K, epi);
}

extern "C" void kernel_launch(void* const* d_in, const int* in_sizes, int n_in,
                              void* d_out, int out_size, void* d_ws, size_t ws_size,
                              hipStream_t stream) {
    const float* x      = (const float*)d_in[0];
    const float* x_prev = (const float*)d_in[1];
    const float* v_first= (const float*)d_in[2];
    const float* state  = (const float*)d_in[3];
    const float* ln1_w  = (const float*)d_in[4];
    const float* ln2_w  = (const float*)d_in[5];
    const float* x_r    = (const float*)d_in[6];
    const float* x_w    = (const float*)d_in[7];
    const float* x_k    = (const float*)d_in[8];
    const float* x_v    = (const float*)d_in[9];
    const float* x_a    = (const float*)d_in[10];
    const float* x_g    = (const float*)d_in[11];
    const float* w0     = (const float*)d_in[12];
    const float* w1     = (const float*)d_in[13];
    const float* w2     = (const float*)d_in[14];
    const float* a0     = (const float*)d_in[15];
    const float* a1     = (const float*)d_in[16];
    const float* a2     = (const float*)d_in[17];
    const float* v0     = (const float*)d_in[18];
    const float* v1     = (const float*)d_in[19];
    const float* v2     = (const float*)d_in[20];
    const float* g1     = (const float*)d_in[21];
    const float* g2     = (const float*)d_in[22];
    const float* k_k    = (const float*)d_in[23];
    const float* k_a    = (const float*)d_in[24];
    const float* r_k    = (const float*)d_in[25];
    const float* R_     = (const float*)d_in[26];
    const float* K_     = (const float*)d_in[27];
    const float* V_     = (const float*)d_in[28];
    const float* O_     = (const float*)d_in[29];
    const float* gate_w = (const float*)d_in[30];
    const float* up_w   = (const float*)d_in[31];
    const float* down_w = (const float*)d_in[32];

    float* ws = (float*)d_ws;
    const size_t U = (size_t)T_ * D_;  // 2M floats
    // fp32 scan-side buffers
    float* u_r  = ws;
    float* u_k  = ws + 1 * U;
    float* u_v  = ws + 2 * U;
    float* u_dc = ws + 3 * U;   // decay; later SstT
    float* u_kk = ws + 4 * U;   // kk;    later o (fix output)
    float* u_mb = ws + 5 * U;   // -kk*a
    float* u_g  = ws + 6 * U;
    float* u_ao = ws + 7 * U;   // a_sig; later Pbuf
    // bf16 activation region: 6 slots of T*D shorts
    ushort* XB = (ushort*)(ws + 8 * U);
    const size_t TD = U;
    ushort* XR = XB + 0 * TD;
    ushort* XW = XB + 1 * TD;
    ushort* XK = XB + 2 * TD;
    ushort* XV = XB + 3 * TD;
    ushort* XA = XB + 4 * TD;
    ushort* XG = XB + 5 * TD;
    ushort* XM   = XB + 0 * TD;  // reuse XR after r-GEMM
    ushort* OG   = XB + 1 * TD;  // reuse XW after w-LoRA1
    ushort* GATE = XB + 2 * TD;  // reuse XK..XG after scan fix
    ushort* UPB  = (ushort*)ws;  // overlay u_r..u_k after bonus
    // chunked-scan overlays
    float* Pbuf  = u_ao;               // [32,16,64,64]
    float* Lbuf  = (float*)XB;         // slots 0-1 (XR/XW dead by pass1)
    float* zbuf  = (float*)(XB + 2 * TD);  // slots 2-3
    float* olbuf = (float*)(XB + 4 * TD);  // slots 4-5
    float* SstT  = u_dc;
    float* obuf  = u_kk;
    // transposed bf16 weights
    ushort* WT = (ushort*)(ws + 11 * U);
    const size_t DD = (size_t)D_ * D_;
    const size_t DF = (size_t)D_ * F_;
    ushort* WTR = WT;
    ushort* WTK = WTR + DD;
    ushort* WTV = WTK + DD;
    ushort* WTO = WTV + DD;
    ushort* WTG = WTO + DD;
    ushort* WTU = WTG + DF;
    ushort* WTD = WTU + DF;
    ushort* WTw1 = WTD + DF;
    ushort* WTw2 = WTw1 + 64 * 1024;
    ushort* WTa1 = WTw2 + 64 * 1024;
    ushort* WTa2 = WTa1 + 64 * 1024;
    ushort* WTv1 = WTa2 + 64 * 1024;
    ushort* WTv2 = WTv1 + 32 * 1024;
    ushort* WTg1 = WTv2 + 32 * 1024;
    ushort* WTg2 = WTg1 + 128 * 1024;
    ushort* Lw = WTg2 + 128 * 1024;
    ushort* La = Lw + (size_t)T_ * 64;
    ushort* Lv = La + (size_t)T_ * 64;
    ushort* Lg = Lv + (size_t)T_ * 32;

    float* out_x = (float*)d_out;
    float* out_xn_last = out_x + (size_t)T_ * D_;
    float* out_state = out_xn_last + D_;

    // --- weight transposes ---
    tc(R_, WTR, D_, D_, stream);
    tc(K_, WTK, D_, D_, stream);
    tc(V_, WTV, D_, D_, stream);
    tc(O_, WTO, D_, D_, stream);
    tc(gate_w, WTG, D_, F_, stream);
    tc(up_w, WTU, D_, F_, stream);
    tc(down_w, WTD, F_, D_, stream);
    tc(w1, WTw1, D_, 64, stream);
    tc(w2, WTw2, 64, D_, stream);
    tc(a1, WTa1, D_, 64, stream);
    tc(a2, WTa2, 64, D_, stream);
    tc(v1, WTv1, D_, 32, stream);
    tc(v2, WTv2, 32, D_, stream);
    tc(g1, WTg1, D_, 128, stream);
    tc(g2, WTg2, 128, D_, stream);

    // 1. ln1 -> xn (in d_out) + xn_last
    rmsnorm_kernel<float><<<T_, 256, 0, stream>>>(x, ln1_w, out_x, out_xn_last);
    // 2. token shift -> bf16 xr..xg
    shift_kernel<<<T_, 256, 0, stream>>>(out_x, x_prev, x_r, x_w, x_k, x_v, x_a, x_g,
                                         XR, XW, XK, XV, XA, XG);
    // 3-5. r/k/v projections
    mm<float>(XR, WTR, u_r, T_, D_, D_, 0, nullptr, nullptr, nullptr, stream);
    mm<float>(XK, WTK, u_k, T_, D_, D_, 0, nullptr, nullptr, nullptr, stream);
    mm<float>(XV, WTV, u_v, T_, D_, D_, 0, nullptr, nullptr, nullptr, stream);
    // 6. LoRA stage-1
    mm<ushort>(XW, WTw1, Lw, T_, 64, D_, 3, nullptr, nullptr, nullptr, stream);   // tanh
    mm<ushort>(XA, WTa1, La, T_, 64, D_, 0, nullptr, nullptr, nullptr, stream);
    mm<ushort>(XV, WTv1, Lv, T_, 32, D_, 0, nullptr, nullptr, nullptr, stream);
    mm<ushort>(XG, WTg1, Lg, T_, 128, D_, 4, nullptr, nullptr, nullptr, stream);  // sigmoid
    // 7. LoRA stage-2 fused epilogues
    mm<float>(Lw, WTw2, u_dc, T_, D_, 64, 6, nullptr, nullptr, w0, stream);       // decay
    mm<float>(La, WTa2, u_ao, T_, D_, 64, 5, nullptr, nullptr, a0, stream);       // a_sig
    mm<float>(Lv, WTv2, u_v, T_, D_, 32, 7, u_v, v_first, v0, stream);            // v lerp
    mm<float>(Lg, WTg2, u_g, T_, D_, 128, 0, nullptr, nullptr, nullptr, stream);  // g
    // 8. kk / mb / k-mod
    kk_kernel<<<T_ * H_, 64, 0, stream>>>(u_k, u_ao, k_k, k_a, u_kk, u_mb);
    // 9. chunked scan
    scan_pass1<<<NCHUNK * H_ * 8, 256, 0, stream>>>(u_r, u_dc, u_k, u_v, u_kk, u_mb,
                                                    Pbuf, Lbuf, zbuf, olbuf);
    scan_combine<<<H_ * 4, 256, 0, stream>>>(state, Pbuf, Lbuf, SstT, out_state);
    scan_fix<<<(T_ / 16) * H_, 256, 0, stream>>>(zbuf, olbuf, SstT, obuf);
    // 10. bonus + gate -> OG bf16
    bonus_kernel<<<T_ * H_, 64, 0, stream>>>(obuf, u_r, u_k, u_v, u_g, r_k, OG);
    // 11. x1 = x + og@O_ -> d_out
    mm<float>(OG, WTO, out_x, T_, D_, D_, 1, x, nullptr, nullptr, stream);
    // 12. ln2 -> xm bf16
    rmsnorm_kernel<ushort><<<T_, 256, 0, stream>>>(out_x, ln2_w, XM, nullptr);
    // 13. MLP
    mm<ushort>(XM, WTG, GATE, T_, F_, D_, 2, nullptr, nullptr, nullptr, stream);  // silu
    mm<ushort>(XM, WTU, UPB, T_, F_, D_, 0, nullptr, nullptr, nullptr, stream);
    mulb_kernel<<<(T_ * F_ / 4) / 256, 256, 0, stream>>>(GATE, UPB);
    // 14. out = x1 + h@down_w
    mm<float>(GATE, WTD, out_x, T_, D_, F_, 1, out_x, nullptr, nullptr, stream);
}